// Round 24
// baseline (33.785 us; speedup 1.0000x reference)
//
#include <hip/hip_runtime.h>

#define KC   21      // num classes
#define BB   8       // batch
#define CC   256     // feat channels
#define HWP  65536   // 256*256 output pixels per image
#define SRC  4096    // 64*64 source pixels
#define NS   32      // chunks: TWO full source rows (128 p) each
#define PC   128     // p per chunk

// d_ws layout: L = 524288 BYTES [0, 524288) | counts f32 @ float idx 131072
// (256 floats, byte 524288) | acc2 f32 @ float idx 131328 ([B][K][C] = 43008
// floats, 172 KB). All disjoint. partial/partialw ELIMINATED (atomic fusion).
#define WSF_COUNTS 131072
#define WSF_ACC2   131328
#define ZTOT_F4    ((256 + BB*KC*CC) / 4)    // 10816 float4 to zero

// ---- k1: per-pixel argmax + gt-match -> label map; zeroes counts+acc2 -------
__global__ __launch_bounds__(256, 2)
void k1_classify(const float* __restrict__ preds,
                 const int*   __restrict__ masks,
                 unsigned char* __restrict__ L,
                 float* __restrict__ zbase)   // counts+acc2 region
{
    int tid = threadIdx.x;
    int idx = blockIdx.x * 256 + tid;            // over B*HWP/4 = 131072

    // zero counts+acc2: 10816 float4 spread across 131072 threads (1 each)
    if (idx < ZTOT_F4)
        reinterpret_cast<float4*>(zbase)[idx] = make_float4(0.f, 0.f, 0.f, 0.f);

    int b   = idx >> 14;
    int hw4 = (idx & 16383) << 2;

    const float* pb = preds + (size_t)b * KC * HWP + hw4;
    float va[4][KC];
#pragma unroll
    for (int k = 0; k < KC; ++k) {
        float4 t = *reinterpret_cast<const float4*>(pb + (size_t)k * HWP);
        va[0][k] = t.x; va[1][k] = t.y; va[2][k] = t.z; va[3][k] = t.w;
    }

    int4 mm = *reinterpret_cast<const int4*>(masks + b * HWP + hw4);
    int mk[4] = { mm.x, mm.y, mm.z, mm.w };

    uchar4 r;
    unsigned char* rp = reinterpret_cast<unsigned char*>(&r);
#pragma unroll
    for (int j = 0; j < 4; ++j) {
        float best = va[j][0];
        int   bi   = 0;
#pragma unroll
        for (int k = 1; k < KC; ++k) {
            if (va[j][k] > best) { best = va[j][k]; bi = k; }  // first-index ties
        }
        rp[j] = (mk[j] == bi) ? (unsigned char)bi : (unsigned char)255;
    }
    *reinterpret_cast<uchar4*>(L + (size_t)b * HWP + hw4) = r;
}

// ---- k2: R23 core; results fused into acc2 via atomics (partial eliminated) -
// Grid (32,8) = 256 blocks = 1/CU x 16 waves (proven-required occupancy).
// psub0 threads fire 21 atomicAdd into acc2 (43K L2-hot addresses, 32
// updates each); counts atomically accumulated (dyadic-exact -> order-
// independent). Replaces 5.5 MB partial write + 5.5 MB k3 read.
__global__ __launch_bounds__(1024, 4)
void k2_contract(const float* __restrict__ feats,      // [B][C][SRC]
                 const unsigned char* __restrict__ L,  // [B][256][256]
                 float* __restrict__ acc2,             // [B][K][C]
                 float* __restrict__ counts)           // [B][K]
{
    __shared__ float ws[KC * PC];         // [21][128] = 10.5 KB gather target
    __shared__ float scr[3 * KC * CC];    // 64.5 KB psub-combine scratch
    int s = blockIdx.x, b = blockIdx.y;   // s = 2-row chunk (rows 2s, 2s+1)
    int tid = threadIdx.x;                // 0..1023
    int p0 = s * PC;
    int ybase = 2 * s;

    int cp   = tid & 255;                 // channel
    int psub = tid >> 8;                  // wave-uniform p-quarter (0..3)
    int pw   = psub * 32;

    for (int t = tid; t < KC * PC / 4; t += 1024)     // zero ws: 672 float4
        *reinterpret_cast<float4*>(ws + t * 4) = make_float4(0.f, 0.f, 0.f, 0.f);

    // feats: own 32-p quarter straight to registers (hidden under gather)
    float f[32];
    {
        const float* frow = feats + (size_t)(b * CC + cp) * SRC + p0 + pw;
#pragma unroll
        for (int q = 0; q < 8; ++q) {
            float4 t = *reinterpret_cast<const float4*>(frow + q * 4);
            f[q * 4 + 0] = t.x; f[q * 4 + 1] = t.y;
            f[q * 4 + 2] = t.z; f[q * 4 + 3] = t.w;
        }
    }
    __syncthreads();                      // ws zeroed

    // gather labels: 12 hi-res rows [8s-2, 8s+9] x 256 cols (R19/R23 pattern)
    {
        int r = tid >> 6, cb = tid & 63;  // 16 groups x 64 threads; use r < 12
        int h = 8 * s - 2 + r;
        if (r < 12 && (unsigned)h < 256u) {
            float sy = h * 0.25f - 0.375f;
            int   yt = (int)floorf(sy);
            float wy = sy - (float)yt;
            int ya = yt < 0 ? 0 : yt;
            int yb = yt + 1 > 63 ? 63 : yt + 1;
            float wyy0 = ((ya == ybase)     ? (1.f - wy) : 0.f) + ((yb == ybase)     ? wy : 0.f);
            float wyy1 = ((ya == ybase + 1) ? (1.f - wy) : 0.f) + ((yb == ybase + 1) ? wy : 0.f);
            if (wyy0 != 0.f || wyy1 != 0.f) {
                const unsigned char* Lrow = L + ((size_t)b << 16) + ((size_t)h << 8);
#pragma unroll
                for (int j = 0; j < 4; ++j) {
                    int w = cb + j * 64;              // all 256 cols
                    int k = Lrow[w];
                    if (k < KC) {
                        float sx = w * 0.25f - 0.375f;
                        int   xt = (int)floorf(sx);
                        float wx = sx - (float)xt;
                        int xa = xt < 0 ? 0 : xt;
                        int xb = xt + 1 > 63 ? 63 : xt + 1;
                        float* wk = ws + k * PC;
                        if (wyy0 != 0.f) {                       // row 2s
                            atomicAdd(wk + xa, wyy0 * (1.f - wx));   // dyadic-exact
                            atomicAdd(wk + xb, wyy0 * wx);
                        }
                        if (wyy1 != 0.f) {                       // row 2s+1
                            atomicAdd(wk + 64 + xa, wyy1 * (1.f - wx));
                            atomicAdd(wk + 64 + xb, wyy1 * wx);
                        }
                    }
                }
            }
        }
    }
    __syncthreads();                      // ws final

    // exact per-chunk class-count contribution (rotated reads; dyadic-exact)
    if (tid < KC) {
        float swcnt = 0.f;
#pragma unroll
        for (int i = 0; i < PC; ++i)
            swcnt += ws[tid * PC + ((i + tid * 8) & (PC - 1))];
        if (swcnt != 0.f)
            atomicAdd(&counts[b * KC + tid], swcnt);  // order-independent
    }

    float acc[KC];
#pragma unroll
    for (int k = 0; k < KC; ++k) {        // fully unrolled, static idx
        const float* wk = ws + k * PC + pw;
        float a0 = 0.f, a1 = 0.f, a2 = 0.f, a3 = 0.f;
#pragma unroll
        for (int q = 0; q < 8; ++q) {
            float4 w4 = *reinterpret_cast<const float4*>(wk + q * 4);  // uniform b128
            a0 += w4.x * f[q * 4 + 0];
            a1 += w4.y * f[q * 4 + 1];
            a2 += w4.z * f[q * 4 + 2];
            a3 += w4.w * f[q * 4 + 3];
        }
        acc[k] = (a0 + a1) + (a2 + a3);
    }

    // 4-way psub combine: psub 1..3 park in scr, psub0 sums -> atomicAdd acc2
    if (psub >= 1) {
        float* sp = scr + (psub - 1) * (KC * CC);
#pragma unroll
        for (int k = 0; k < KC; ++k) sp[k * CC + cp] = acc[k];
    }
    __syncthreads();
    if (psub == 0) {
        float* ap = acc2 + (size_t)(b * KC) * CC + cp;
#pragma unroll
        for (int k = 0; k < KC; ++k) {
            float v = acc[k] + scr[k * CC + cp]
                             + scr[KC * CC + k * CC + cp]
                             + scr[2 * KC * CC + k * CC + cp];
            atomicAdd(ap + (size_t)k * CC, v);    // fire-and-forget, L2-hot
        }
    }
}

// ---- k3: normalize + batch-mean from acc2 (172 KB read, single write) -------
__global__ __launch_bounds__(256)
void k3_finalize(const float* __restrict__ acc2,    // [B][K][C]
                 const float* __restrict__ counts,  // [B][K]
                 float* __restrict__ out)           // [K][C]
{
    int k = blockIdx.x;    // 21
    int c = threadIdx.x;   // 256

    float r = 0.f;
#pragma unroll
    for (int b = 0; b < BB; ++b) {
        float cnt = counts[b * KC + k];            // uniform scalar load
        r += acc2[(size_t)(b * KC + k) * CC + c] / (cnt + 1e-6f);
    }
    out[k * CC + c] = r * 0.125f;                  // written once
}

extern "C" void kernel_launch(void* const* d_in, const int* in_sizes, int n_in,
                              void* d_out, int out_size, void* d_ws, size_t ws_size,
                              hipStream_t stream) {
    const float* feats = (const float*)d_in[0];   // [8,256,64,64]
    const float* preds = (const float*)d_in[1];   // [8,21,256,256]
    const int*   masks = (const int*)  d_in[2];   // [8,256,256]
    float* out = (float*)d_out;                   // [21,256]

    float* wsf = (float*)d_ws;
    unsigned char* L = (unsigned char*)d_ws;      // 524288 bytes, fully written by k1
    float* counts = wsf + WSF_COUNTS;             // byte 524288: disjoint from L
    float* acc2   = wsf + WSF_ACC2;

    k1_classify<<<(BB * HWP / 4) / 256, 256, 0, stream>>>(preds, masks, L, counts);
    k2_contract<<<dim3(NS, BB), 1024, 0, stream>>>(feats, L, acc2, counts);
    k3_finalize<<<KC, 256, 0, stream>>>(acc2, counts, out);
}